// Round 1
// 543.603 us; speedup vs baseline: 1.2511x; 1.2511x over previous
//
#include <hip/hip_runtime.h>

#define NBS    256
#define NELEC  64
#define NPART  80
#define NBASIS 32
#define KD     128
#define DD     128
#define IB     8     // i's per cfconv block

#define LOG2E 1.4426950408889634f
#define LN2   0.69314718055994530942f

typedef short v8s __attribute__((ext_vector_type(8)));
typedef float v4f __attribute__((ext_vector_type(4)));
typedef __bf16 bf2 __attribute__((ext_vector_type(2)));

#if __has_builtin(__builtin_amdgcn_exp2f)
#define EXP2F(x) __builtin_amdgcn_exp2f(x)
#else
#define EXP2F(x) __expf((x) * LN2)
#endif
#if __has_builtin(__builtin_amdgcn_logf)
#define LOG2F(x) __builtin_amdgcn_logf(x)
#else
#define LOG2F(x) __log2f(x)
#endif

// shifted softplus on a pre-scaled input: y = log2e * x
// ssp(x) = ln2*log2(1 + 2^y) - ln2   (4 VALU ops, 2 trans)
__device__ __forceinline__ float sspf2(float y) {
    float t = 1.0f + EXP2F(y);
    return __builtin_fmaf(LOG2F(t), LN2, -LN2);
}

__device__ __forceinline__ float bf2f(unsigned short u) {
    unsigned int x = ((unsigned int)u) << 16;
    return __builtin_bit_cast(float, x);
}
// native bf16 convert (RNE) — compiler selects v_cvt_pk_bf16_f32 on gfx950
__device__ __forceinline__ unsigned short f2bf(float f) {
    return __builtin_bit_cast(unsigned short, (__bf16)f);
}
__device__ __forceinline__ unsigned int pk2(float lo, float hi) {
    bf2 p;
    p.x = (__bf16)lo;
    p.y = (__bf16)hi;
    return __builtin_bit_cast(unsigned int, p);
}

// xs[b,i,:] = embedding_elec[i,:] (f32 master + bf16 mirror)
__global__ __launch_bounds__(256) void k_init_xs(const float* __restrict__ emb,
                                                 float* __restrict__ xs,
                                                 unsigned short* __restrict__ xs_bf) {
    int idx = blockIdx.x * 256 + threadIdx.x;
    float v = emb[idx & (NELEC * DD - 1)];
    xs[idx] = v;
    xs_bf[idx] = f2bf(v);
}

// zsbf nuc rows: zsbf[b, 64+j, k] = bf16(nuc[j,k])
__global__ __launch_bounds__(256) void k_nuc(const float* __restrict__ nuc,
                                             unsigned short* __restrict__ zsbf) {
    int idx = blockIdx.x * 256 + threadIdx.x;           // < 256*16*128
    int b = idx >> 11;
    int rem = idx & 2047;
    zsbf[(size_t)b * (NPART * KD) + NELEC * KD + rem] = f2bf(nuc[rem]);
}

// Pre-swizzle kW1/kW2 (per layer) into MFMA A-operand fragment order, bf16.
// kW1 is pre-scaled by log2e so GEMM1's output is already log2e*(d@kW1+kb1).
__global__ __launch_bounds__(256) void k_prep(const float* __restrict__ kW1g,
                                              const float* __restrict__ kW2g,
                                              unsigned short* __restrict__ kW1Tf,
                                              unsigned short* __restrict__ kW2Tf) {
    const int l = blockIdx.x;
    const int t = threadIdx.x;
    for (int e = 0; e < 64; ++e) {
        int o = e * 256 + t;                       // < 16384
        int mt = o >> 11, ks = (o >> 9) & 3, lane = (o >> 3) & 63, jj = o & 7;
        int q = lane >> 4, cc = lane & 15;
        int kf = ks * 32 + q * 8 + jj;
        int kcol = mt * 16 + cc;
        kW2Tf[(size_t)l * 16384 + o] = f2bf(kW2g[(size_t)l * 16384 + kf * 128 + kcol]);
    }
    for (int e = 0; e < 16; ++e) {
        int o = e * 256 + t;                       // < 4096
        int kct = o >> 9, lane = (o >> 3) & 63, jj = o & 7;
        int q = lane >> 4, cc = lane & 15;
        int f = q * 8 + jj;
        int kcol = kct * 16 + cc;
        kW1Tf[(size_t)l * 4096 + o] = f2bf(kW1g[(size_t)l * 4096 + f * 128 + kcol] * LOG2E);
    }
}

// B-operand fragment swizzle for the small gemms' weights (9 matrices 128x128).
// eoW1 (which==1) is pre-scaled by log2e for the exp2-based ssp in MODE 1.
__global__ __launch_bounds__(256) void k_prep_w(const float* __restrict__ eiW,
                                                const float* __restrict__ eoW1,
                                                const float* __restrict__ eoW2,
                                                unsigned short* __restrict__ Wf) {
    const int bi = blockIdx.x;          // 0..8 : which*3 + l
    const int which = bi / 3, l = bi % 3;
    const float* src = (which == 0 ? eiW : which == 1 ? eoW1 : eoW2) + (size_t)l * 16384;
    unsigned short* dst = Wf + (size_t)bi * 16384;
    const float s = (which == 1) ? LOG2E : 1.0f;
    const int t = threadIdx.x;
    for (int e = 0; e < 64; ++e) {
        int o = e * 256 + t;
        int mt = o >> 11, ks = (o >> 9) & 3, lane = (o >> 3) & 63, jj = o & 7;
        int q = lane >> 4, cc = lane & 15;
        dst[o] = f2bf(src[(ks * 32 + q * 8 + jj) * 128 + mt * 16 + cc] * s);
    }
}

// bias fragments for cfconv: [l][w(4)][lane(64)][e(8)]: e = mt*4+r -> kb[l*128 + (2*w+mt)*16 + q*4 + r]
// kb1 pre-scaled by log2e (matches pre-scaled kW1).
__global__ __launch_bounds__(256) void k_prep_misc(const float* __restrict__ kb1,
                                                   const float* __restrict__ kb2,
                                                   float* __restrict__ kb1f,
                                                   float* __restrict__ kb2f) {
    const int t = threadIdx.x;
    for (int o = t; o < 3 * 4 * 64 * 8; o += 256) {
        int l = o >> 11, rem = o & 2047;
        int w = rem >> 9, lane = (rem >> 3) & 63, e = o & 7;
        int mt = e >> 2, r = e & 3, q = lane >> 4;
        int kcol = (2 * w + mt) * 16 + q * 4 + r;
        kb1f[o] = kb1[l * 128 + kcol] * LOG2E;
        kb2f[o] = kb2[l * 128 + kcol];
    }
}

// MFMA small gemm: C(64x128) = X(64x128,bf16) @ W(frag bf16)  [+bias][+ssp]
// MODE 0: zs; MODE 1: h (bias+ssp, W and bias pre-scaled by log2e); MODE 2: xs += C
template <int MODE>
__global__ __launch_bounds__(256) void k_gemm(
    const unsigned short* __restrict__ Xbf,
    const unsigned short* __restrict__ Wf,
    const float* __restrict__ bias,
    unsigned short* __restrict__ Obf,
    float* __restrict__ Of,
    int ostride) {
    const int blk = blockIdx.x;
    const int b = blk >> 1, kh2 = blk & 1;
    const int t = threadIdx.x, lane = t & 63, w = t >> 6;
    const int q = lane >> 4, c = lane & 15;

    const unsigned short* xb = Xbf + (size_t)b * (NELEC * KD);
    v8s A[4];
#pragma unroll
    for (int ks = 0; ks < 4; ++ks)
        A[ks] = *(const v8s*)(xb + (w * 16 + c) * 128 + ks * 32 + q * 8);

#pragma unroll
    for (int kt = 0; kt < 4; ++kt) {
        const int n0 = kh2 * 64 + kt * 16;
        float bv = (MODE >= 1) ? bias[n0 + c] : 0.0f;
        if (MODE == 1) bv *= LOG2E;
        v4f acc = {bv, bv, bv, bv};
#pragma unroll
        for (int ks = 0; ks < 4; ++ks) {
            v8s B = *(const v8s*)(Wf + (((size_t)(kh2 * 4 + kt) * 4 + ks) * 64 + lane) * 8);
            acc = __builtin_amdgcn_mfma_f32_16x16x32_bf16(A[ks], B, acc, 0, 0, 0);
        }
#pragma unroll
        for (int r = 0; r < 4; ++r) {
            float v = acc[r];
            if (MODE == 1) v = sspf2(v);
            int row = w * 16 + q * 4 + r, col = n0 + c;
            if (MODE == 2) {
                size_t o = (size_t)b * (NELEC * KD) + row * 128 + col;
                float nv = Of[o] + v;
                Of[o] = nv;
                Obf[o] = f2bf(nv);
            } else {
                Obf[(size_t)b * ostride + row * 128 + col] = f2bf(v);
            }
        }
    }
}

// One block per (b, group of IB i's). Transposed MFMA formulation, no k-split:
// wave w owns kcols [w*32, w*32+32) (tiles 2w, 2w+1) with the FULL K sum.
//   GEMM1-T: X1T[kcol][j] = ssp( sum_f kW1T[kcol][f]*dists[j][f] + kb1[kcol] )
//   GEMM2-T: WsT[kcol][j] = sum_kf kW2T[kcol][kf]*X1T[kf][j] + kb2[kcol]
//   agg[kcol] = sum_j WsT[kcol][j]*zs[b][j][kcol]  (j==i masked, uniform-branched)
__global__ __launch_bounds__(256, 2) void k_cfconv_mfma(
    const float* __restrict__ dists,
    const float* __restrict__ kb1f, const float* __restrict__ kb2f,
    const unsigned short* __restrict__ zsbf,
    const unsigned short* __restrict__ kW1Tf,
    const unsigned short* __restrict__ kW2Tf,
    unsigned short* __restrict__ aggbf, int l) {
    __shared__ __align__(16) unsigned short s_dists[2560];   // [jt(5)][lane(64)][jj(8)]
    __shared__ __align__(16) unsigned short s_X1[10240];     // [jt(5)][ks(4)][lane(64)][jj(8)]

    const int blk = blockIdx.x;
    const int b = blk >> 3;          // 64/IB = 8 groups
    const int ig = blk & 7;
    const int t = threadIdx.x;
    const int lane = t & 63;
    const int w = t >> 6;
    const int q = lane >> 4;
    const int c = lane & 15;

    // --- per-block prelude: weights, biases, zs (amortized over IB i's) ---
    v8s a1[2], a2[2][4];
    {
        const uint4* w1p = (const uint4*)kW1Tf;
        const uint4* w2p = (const uint4*)kW2Tf;
#pragma unroll
        for (int t1 = 0; t1 < 2; ++t1) {
            uint4 u = w1p[(l * 8 + 2 * w + t1) * 64 + lane];
            a1[t1] = __builtin_bit_cast(v8s, u);
        }
#pragma unroll
        for (int mt = 0; mt < 2; ++mt)
#pragma unroll
            for (int ks = 0; ks < 4; ++ks) {
                uint4 u = w2p[((l * 8 + 2 * w + mt) * 4 + ks) * 64 + lane];
                a2[mt][ks] = __builtin_bit_cast(v8s, u);
            }
    }
    float4 kb1v[2], kb2v[2];
    {
        const float4* p1 = (const float4*)(kb1f + ((size_t)(l * 4 + w) * 64 + lane) * 8);
        kb1v[0] = p1[0];
        kb1v[1] = p1[1];
        const float4* p2 = (const float4*)(kb2f + ((size_t)(l * 4 + w) * 64 + lane) * 8);
        kb2v[0] = p2[0];
        kb2v[1] = p2[1];
    }
    // zs values exactly at this lane's reduce positions: row j=jt*16+c, col w*32+mt*16+q*4+r
    float zf[2][5][4];
    {
        const unsigned short* zb = zsbf + (size_t)b * (NPART * KD) + w * 32 + q * 4;
#pragma unroll
        for (int mt = 0; mt < 2; ++mt)
#pragma unroll
            for (int jt = 0; jt < 5; ++jt) {
                ushort4 zv = *(const ushort4*)(zb + (jt * 16 + c) * 128 + mt * 16);
                zf[mt][jt][0] = bf2f(zv.x);
                zf[mt][jt][1] = bf2f(zv.y);
                zf[mt][jt][2] = bf2f(zv.z);
                zf[mt][jt][3] = bf2f(zv.w);
            }
    }

    const float* dbase = dists + ((size_t)b * NELEC + ig * IB) * (NPART * NBASIS);

#pragma unroll 1
    for (int ii = 0; ii < IB; ++ii) {
        const int i = ig * IB + ii;

        // stage dists(b,i) into B-frag order: float4 gather + b128 LDS writes
        {
            const float* dg = dbase + (size_t)ii * (NPART * NBASIS);
            for (int jt = w; jt < 5; jt += 4) {
                const float* dj = dg + (jt * 16 + c) * 32 + q * 8;
                float4 v0 = *(const float4*)dj;
                float4 v1 = *(const float4*)(dj + 4);
                uint4 pk;
                pk.x = pk2(v0.x, v0.y);
                pk.y = pk2(v0.z, v0.w);
                pk.z = pk2(v1.x, v1.y);
                pk.w = pk2(v1.z, v1.w);
                *(uint4*)(s_dists + (jt * 64 + lane) * 8) = pk;
            }
        }
        __syncthreads();

        // GEMM1-T: 10 MFMA, ssp (exp2-form, weights pre-scaled), write X1 B-frags
#pragma unroll
        for (int jt = 0; jt < 5; ++jt) {
            v8s bd = *(const v8s*)(s_dists + (jt * 64 + lane) * 8);
#pragma unroll
            for (int t1 = 0; t1 < 2; ++t1) {
                v4f d = {kb1v[t1].x, kb1v[t1].y, kb1v[t1].z, kb1v[t1].w};
                d = __builtin_amdgcn_mfma_f32_16x16x32_bf16(a1[t1], bd, d, 0, 0, 0);
                uint2 o;
                o.x = pk2(sspf2(d[0]), sspf2(d[1]));
                o.y = pk2(sspf2(d[2]), sspf2(d[3]));
                int qB = 2 * t1 + (q >> 1);   // ks slice = w (wave owns kcols w*32..)
                *(uint2*)(s_X1 + ((jt * 4 + w) * 64 + qB * 16 + c) * 8 + (q & 1) * 4) = o;
            }
        }
        __syncthreads();

        // GEMM2-T: 40 MFMA over (2 mt, 5 jt, 4 ks), full K sum per wave
        v4f acc[2][5];
#pragma unroll
        for (int mt = 0; mt < 2; ++mt)
#pragma unroll
            for (int jt = 0; jt < 5; ++jt)
                acc[mt][jt] = (v4f){(&kb2v[mt].x)[0], (&kb2v[mt].x)[1],
                                    (&kb2v[mt].x)[2], (&kb2v[mt].x)[3]};

#pragma unroll
        for (int jt = 0; jt < 5; ++jt) {
#pragma unroll
            for (int ks = 0; ks < 4; ++ks) {
                v8s bx = *(const v8s*)(s_X1 + ((jt * 4 + ks) * 64 + lane) * 8);
                acc[0][jt] = __builtin_amdgcn_mfma_f32_16x16x32_bf16(a2[0][ks], bx, acc[0][jt], 0, 0, 0);
                acc[1][jt] = __builtin_amdgcn_mfma_f32_16x16x32_bf16(a2[1][ks], bx, acc[1][jt], 0, 0, 0);
            }
        }

        // weighted reduce over j with the j==i diagonal masked.
        // i is block-uniform: only the jt == i>>4 tile needs a per-lane cndmask,
        // selected by a compile-time-unrolled uniform branch (saves 32 cndmasks).
        float red[8];
#pragma unroll
        for (int v = 0; v < 8; ++v) red[v] = 0.0f;
        const int jt_i = i >> 4;
        const bool lanehit = (c == (i & 15));
#pragma unroll
        for (int jt = 0; jt < 5; ++jt) {
            if (jt == jt_i) {
#pragma unroll
                for (int mt = 0; mt < 2; ++mt)
#pragma unroll
                    for (int r = 0; r < 4; ++r) {
                        float a = lanehit ? 0.0f : acc[mt][jt][r];
                        red[mt * 4 + r] += a * zf[mt][jt][r];
                    }
            } else {
#pragma unroll
                for (int mt = 0; mt < 2; ++mt)
#pragma unroll
                    for (int r = 0; r < 4; ++r)
                        red[mt * 4 + r] += acc[mt][jt][r] * zf[mt][jt][r];
            }
        }

        // butterfly: 8 vals -> lane c holds value (c&7) summed over its 8-lane half,
        // then xor-8 add completes the 16-lane j sum.
        float vals[8];
#pragma unroll
        for (int v = 0; v < 8; ++v) vals[v] = red[v];
#pragma unroll
        for (int B = 0; B < 3; ++B) {
            const int off = 1 << B;
            const bool up = (c >> B) & 1;
#pragma unroll
            for (int k2 = 0; k2 < (4 >> B); ++k2) {
                float aa = vals[2 * k2], bb = vals[2 * k2 + 1];
                float mine = up ? bb : aa;
                float other = up ? aa : bb;
                vals[k2] = mine + __shfl_xor(other, off, 64);
            }
        }
        float x = vals[0] + __shfl_xor(vals[0], 8, 64);

        // lanes c<8 write this wave's 32 kcols: kcol = w*32 + ((c>>2)&1)*16 + q*4 + (c&3)
        if (c < 8) {
            int kcol = w * 32 + ((c >> 2) & 1) * 16 + q * 4 + (c & 3);
            aggbf[((size_t)b * NELEC + i) * 128 + kcol] = f2bf(x);
        }
    }
}

extern "C" void kernel_launch(void* const* d_in, const int* in_sizes, int n_in,
                              void* d_out, int out_size, void* d_ws, size_t ws_size,
                              hipStream_t stream) {
    const float* dists = (const float*)d_in[0];
    const float* emb_e = (const float*)d_in[1];
    const float* emb_n = (const float*)d_in[2];
    const float* kW1   = (const float*)d_in[3];
    const float* kb1   = (const float*)d_in[4];
    const float* kW2   = (const float*)d_in[5];
    const float* kb2   = (const float*)d_in[6];
    const float* eiW   = (const float*)d_in[7];
    const float* eoW1  = (const float*)d_in[8];
    const float* eob1  = (const float*)d_in[9];
    const float* eoW2  = (const float*)d_in[10];
    const float* eob2  = (const float*)d_in[11];

    float* xs = (float*)d_out;                                  // (256,64,128) f32
    unsigned short* zsbf  = (unsigned short*)d_ws;              // (256,80,128) bf16
    unsigned short* aggbf = zsbf + NBS * NPART * KD;            // (256,64,128) bf16
    unsigned short* hbf   = aggbf + NBS * NELEC * KD;           // (256,64,128) bf16
    unsigned short* xs_bf = hbf + NBS * NELEC * KD;             // (256,64,128) bf16
    unsigned short* kW1Tf = xs_bf + NBS * NELEC * KD;           // 3*4096
    unsigned short* kW2Tf = kW1Tf + 3 * 4096;                   // 3*16384
    unsigned short* Wf    = kW2Tf + 3 * 16384;                  // 9*16384
    float* kb1f = (float*)(Wf + 9 * 16384);                     // 6144 f32
    float* kb2f = kb1f + 3 * 4 * 64 * 8;                        // 6144 f32

    k_init_xs<<<(NBS * NELEC * DD) / 256, 256, 0, stream>>>(emb_e, xs, xs_bf);
    k_prep<<<3, 256, 0, stream>>>(kW1, kW2, kW1Tf, kW2Tf);
    k_prep_w<<<9, 256, 0, stream>>>(eiW, eoW1, eoW2, Wf);
    k_prep_misc<<<1, 256, 0, stream>>>(kb1, kb2, kb1f, kb2f);
    k_nuc<<<(NBS * 16 * KD) / 256, 256, 0, stream>>>(emb_n, zsbf);

    for (int l = 0; l < 3; ++l) {
        // zs[:, :64] (bf16) = xs_bf @ eiW[l]
        k_gemm<0><<<NBS * 2, 256, 0, stream>>>(
            xs_bf, Wf + (size_t)(0 * 3 + l) * 16384, nullptr, zsbf, nullptr, NPART * KD);

        k_cfconv_mfma<<<NBS * (NELEC / IB), 256, 0, stream>>>(
            dists, kb1f, kb2f, zsbf, kW1Tf, kW2Tf, aggbf, l);

        // h (bf16) = ssp(agg @ eoW1 + eob1)   (exp2-form, weights/bias pre-scaled)
        k_gemm<1><<<NBS * 2, 256, 0, stream>>>(
            aggbf, Wf + (size_t)(1 * 3 + l) * 16384, eob1 + l * DD, hbf, nullptr, NELEC * KD);

        // xs += h @ eoW2 + eob2   (f32 master + bf16 mirror)
        k_gemm<2><<<NBS * 2, 256, 0, stream>>>(
            hbf, Wf + (size_t)(2 * 3 + l) * 16384, eob2 + l * DD, xs_bf, xs, NELEC * KD);
    }
}

// Round 2
// 525.644 us; speedup vs baseline: 1.2938x; 1.0342x over previous
//
#include <hip/hip_runtime.h>

#define NBS    256
#define NELEC  64
#define NPART  80
#define NBASIS 32
#define KD     128
#define DD     128
#define IB     8     // i's per cfconv block

#define LOG2E 1.4426950408889634f
#define LN2   0.69314718055994530942f

typedef short v8s __attribute__((ext_vector_type(8)));
typedef float v4f __attribute__((ext_vector_type(4)));
typedef __bf16 bf2 __attribute__((ext_vector_type(2)));

#if __has_builtin(__builtin_amdgcn_exp2f)
#define EXP2F(x) __builtin_amdgcn_exp2f(x)
#else
#define EXP2F(x) __expf((x) * LN2)
#endif
#if __has_builtin(__builtin_amdgcn_logf)
#define LOG2F(x) __builtin_amdgcn_logf(x)
#else
#define LOG2F(x) __log2f(x)
#endif

// shifted softplus on a pre-scaled input: y = log2e * x
// ssp(x) = ln2*log2(1 + 2^y) - ln2   (4 VALU ops, 2 trans)
__device__ __forceinline__ float sspf2(float y) {
    float t = 1.0f + EXP2F(y);
    return __builtin_fmaf(LOG2F(t), LN2, -LN2);
}

__device__ __forceinline__ float bf2f(unsigned short u) {
    unsigned int x = ((unsigned int)u) << 16;
    return __builtin_bit_cast(float, x);
}
// native bf16 convert (RNE) — compiler selects v_cvt_pk_bf16_f32 on gfx950
__device__ __forceinline__ unsigned short f2bf(float f) {
    return __builtin_bit_cast(unsigned short, (__bf16)f);
}
__device__ __forceinline__ unsigned int pk2(float lo, float hi) {
    bf2 p;
    p.x = (__bf16)lo;
    p.y = (__bf16)hi;
    return __builtin_bit_cast(unsigned int, p);
}

// xs[b,i,:] = embedding_elec[i,:] (f32 master + bf16 mirror)
__global__ __launch_bounds__(256) void k_init_xs(const float* __restrict__ emb,
                                                 float* __restrict__ xs,
                                                 unsigned short* __restrict__ xs_bf) {
    int idx = blockIdx.x * 256 + threadIdx.x;
    float v = emb[idx & (NELEC * DD - 1)];
    xs[idx] = v;
    xs_bf[idx] = f2bf(v);
}

// zsbf nuc rows: zsbf[b, 64+j, k] = bf16(nuc[j,k])
__global__ __launch_bounds__(256) void k_nuc(const float* __restrict__ nuc,
                                             unsigned short* __restrict__ zsbf) {
    int idx = blockIdx.x * 256 + threadIdx.x;           // < 256*16*128
    int b = idx >> 11;
    int rem = idx & 2047;
    zsbf[(size_t)b * (NPART * KD) + NELEC * KD + rem] = f2bf(nuc[rem]);
}

// Pre-swizzle kW1/kW2 (per layer) into MFMA A-operand fragment order, bf16.
// kW1 is pre-scaled by log2e so GEMM1's output is already log2e*(d@kW1+kb1).
__global__ __launch_bounds__(256) void k_prep(const float* __restrict__ kW1g,
                                              const float* __restrict__ kW2g,
                                              unsigned short* __restrict__ kW1Tf,
                                              unsigned short* __restrict__ kW2Tf) {
    const int l = blockIdx.x;
    const int t = threadIdx.x;
    for (int e = 0; e < 64; ++e) {
        int o = e * 256 + t;                       // < 16384
        int mt = o >> 11, ks = (o >> 9) & 3, lane = (o >> 3) & 63, jj = o & 7;
        int q = lane >> 4, cc = lane & 15;
        int kf = ks * 32 + q * 8 + jj;
        int kcol = mt * 16 + cc;
        kW2Tf[(size_t)l * 16384 + o] = f2bf(kW2g[(size_t)l * 16384 + kf * 128 + kcol]);
    }
    for (int e = 0; e < 16; ++e) {
        int o = e * 256 + t;                       // < 4096
        int kct = o >> 9, lane = (o >> 3) & 63, jj = o & 7;
        int q = lane >> 4, cc = lane & 15;
        int f = q * 8 + jj;
        int kcol = kct * 16 + cc;
        kW1Tf[(size_t)l * 4096 + o] = f2bf(kW1g[(size_t)l * 4096 + f * 128 + kcol] * LOG2E);
    }
}

// B-operand fragment swizzle for the small gemms' weights (9 matrices 128x128).
// eoW1 (which==1) is pre-scaled by log2e for the exp2-based ssp.
__global__ __launch_bounds__(256) void k_prep_w(const float* __restrict__ eiW,
                                                const float* __restrict__ eoW1,
                                                const float* __restrict__ eoW2,
                                                unsigned short* __restrict__ Wf) {
    const int bi = blockIdx.x;          // 0..8 : which*3 + l
    const int which = bi / 3, l = bi % 3;
    const float* src = (which == 0 ? eiW : which == 1 ? eoW1 : eoW2) + (size_t)l * 16384;
    unsigned short* dst = Wf + (size_t)bi * 16384;
    const float s = (which == 1) ? LOG2E : 1.0f;
    const int t = threadIdx.x;
    for (int e = 0; e < 64; ++e) {
        int o = e * 256 + t;
        int mt = o >> 11, ks = (o >> 9) & 3, lane = (o >> 3) & 63, jj = o & 7;
        int q = lane >> 4, cc = lane & 15;
        dst[o] = f2bf(src[(ks * 32 + q * 8 + jj) * 128 + mt * 16 + cc] * s);
    }
}

// bias fragments for cfconv: [l][w(4)][lane(64)][e(8)]: e = mt*4+r -> kb[l*128 + (2*w+mt)*16 + q*4 + r]
// kb1 pre-scaled by log2e (matches pre-scaled kW1).
__global__ __launch_bounds__(256) void k_prep_misc(const float* __restrict__ kb1,
                                                   const float* __restrict__ kb2,
                                                   float* __restrict__ kb1f,
                                                   float* __restrict__ kb2f) {
    const int t = threadIdx.x;
    for (int o = t; o < 3 * 4 * 64 * 8; o += 256) {
        int l = o >> 11, rem = o & 2047;
        int w = rem >> 9, lane = (rem >> 3) & 63, e = o & 7;
        int mt = e >> 2, r = e & 3, q = lane >> 4;
        int kcol = (2 * w + mt) * 16 + q * 4 + r;
        kb1f[o] = kb1[l * 128 + kcol] * LOG2E;
        kb2f[o] = kb2[l * 128 + kcol];
    }
}

// MFMA small gemm: C(64x128) = X(64x128,bf16) @ W(frag bf16)   (MODE 0 only used now)
template <int MODE>
__global__ __launch_bounds__(256) void k_gemm(
    const unsigned short* __restrict__ Xbf,
    const unsigned short* __restrict__ Wf,
    const float* __restrict__ bias,
    unsigned short* __restrict__ Obf,
    float* __restrict__ Of,
    int ostride) {
    const int blk = blockIdx.x;
    const int b = blk >> 1, kh2 = blk & 1;
    const int t = threadIdx.x, lane = t & 63, w = t >> 6;
    const int q = lane >> 4, c = lane & 15;

    const unsigned short* xb = Xbf + (size_t)b * (NELEC * KD);
    v8s A[4];
#pragma unroll
    for (int ks = 0; ks < 4; ++ks)
        A[ks] = *(const v8s*)(xb + (w * 16 + c) * 128 + ks * 32 + q * 8);

#pragma unroll
    for (int kt = 0; kt < 4; ++kt) {
        const int n0 = kh2 * 64 + kt * 16;
        float bv = (MODE >= 1) ? bias[n0 + c] : 0.0f;
        if (MODE == 1) bv *= LOG2E;
        v4f acc = {bv, bv, bv, bv};
#pragma unroll
        for (int ks = 0; ks < 4; ++ks) {
            v8s B = *(const v8s*)(Wf + (((size_t)(kh2 * 4 + kt) * 4 + ks) * 64 + lane) * 8);
            acc = __builtin_amdgcn_mfma_f32_16x16x32_bf16(A[ks], B, acc, 0, 0, 0);
        }
#pragma unroll
        for (int r = 0; r < 4; ++r) {
            float v = acc[r];
            if (MODE == 1) v = sspf2(v);
            int row = w * 16 + q * 4 + r, col = n0 + c;
            if (MODE == 2) {
                size_t o = (size_t)b * (NELEC * KD) + row * 128 + col;
                float nv = Of[o] + v;
                Of[o] = nv;
                Obf[o] = f2bf(nv);
            } else {
                Obf[(size_t)b * ostride + row * 128 + col] = f2bf(v);
            }
        }
    }
}

// Fused tail per layer: h = ssp(agg@eoW1+b1); xs += h@eoW2+b2; (if !LAST) zs = xs@eiW[l+1].
// One block per b, 512 threads (8 waves: wr = row-tile, kh = kt-half).
// h / xs_new staged in LDS f32 with stride 129 (odd dword -> 2-way banks, free).
template <int LAST>
__global__ __launch_bounds__(512) void k_tail(
    const unsigned short* __restrict__ aggbf,
    const unsigned short* __restrict__ WfA,   // eoW1 frag (pre-scaled log2e)
    const float* __restrict__ b1,             // eob1 + l*128
    const unsigned short* __restrict__ WfB,   // eoW2 frag
    const float* __restrict__ b2,             // eob2 + l*128
    const unsigned short* __restrict__ WfC,   // eiW frag (l+1), unused if LAST
    float* __restrict__ xs,
    unsigned short* __restrict__ xs_bf,
    unsigned short* __restrict__ zsbf) {
    __shared__ float hl[64 * 129];
    const int b = blockIdx.x;
    const int t = threadIdx.x, lane = t & 63, w = t >> 6;
    const int wr = w & 3, kh = w >> 2;
    const int q = lane >> 4, c = lane & 15;

    const unsigned short* ab = aggbf + (size_t)b * (NELEC * KD);
    v8s A[4];
#pragma unroll
    for (int ks = 0; ks < 4; ++ks)
        A[ks] = *(const v8s*)(ab + (wr * 16 + c) * 128 + ks * 32 + q * 8);

    // phase 1: h = ssp(agg @ eoW1 + b1) -> hl (f32)
#pragma unroll
    for (int kt2 = 0; kt2 < 4; ++kt2) {
        const int kt = kh * 4 + kt2;
        float bv = b1[kt * 16 + c] * LOG2E;
        v4f acc = {bv, bv, bv, bv};
#pragma unroll
        for (int ks = 0; ks < 4; ++ks) {
            v8s B = *(const v8s*)(WfA + (((size_t)kt * 4 + ks) * 64 + lane) * 8);
            acc = __builtin_amdgcn_mfma_f32_16x16x32_bf16(A[ks], B, acc, 0, 0, 0);
        }
#pragma unroll
        for (int r = 0; r < 4; ++r)
            hl[(wr * 16 + q * 4 + r) * 129 + kt * 16 + c] = sspf2(acc[r]);
    }
    __syncthreads();
    // A2 frags from hl
#pragma unroll
    for (int ks = 0; ks < 4; ++ks) {
        const float* hp = hl + (wr * 16 + c) * 129 + ks * 32 + q * 8;
        uint4 u;
        u.x = pk2(hp[0], hp[1]);
        u.y = pk2(hp[2], hp[3]);
        u.z = pk2(hp[4], hp[5]);
        u.w = pk2(hp[6], hp[7]);
        A[ks] = __builtin_bit_cast(v8s, u);
    }
    __syncthreads();   // all A2 reads done before epilogue overwrites hl

    // phase 2: xs += h @ eoW2 + b2 (f32 master + bf16 mirror); stash xs_new in hl
    float* xb = xs + (size_t)b * (NELEC * DD);
    unsigned short* xbb = xs_bf + (size_t)b * (NELEC * DD);
#pragma unroll
    for (int kt2 = 0; kt2 < 4; ++kt2) {
        const int kt = kh * 4 + kt2;
        float bv = b2[kt * 16 + c];
        v4f acc = {bv, bv, bv, bv};
#pragma unroll
        for (int ks = 0; ks < 4; ++ks) {
            v8s B = *(const v8s*)(WfB + (((size_t)kt * 4 + ks) * 64 + lane) * 8);
            acc = __builtin_amdgcn_mfma_f32_16x16x32_bf16(A[ks], B, acc, 0, 0, 0);
        }
#pragma unroll
        for (int r = 0; r < 4; ++r) {
            int row = wr * 16 + q * 4 + r, col = kt * 16 + c;
            float nv = xb[row * 128 + col] + acc[r];
            xb[row * 128 + col] = nv;
            xbb[row * 128 + col] = f2bf(nv);
            if (!LAST) hl[row * 129 + col] = nv;
        }
    }
    if (!LAST) {
        __syncthreads();
#pragma unroll
        for (int ks = 0; ks < 4; ++ks) {
            const float* hp = hl + (wr * 16 + c) * 129 + ks * 32 + q * 8;
            uint4 u;
            u.x = pk2(hp[0], hp[1]);
            u.y = pk2(hp[2], hp[3]);
            u.z = pk2(hp[4], hp[5]);
            u.w = pk2(hp[6], hp[7]);
            A[ks] = __builtin_bit_cast(v8s, u);
        }
        unsigned short* zb = zsbf + (size_t)b * (NPART * KD);
#pragma unroll
        for (int kt2 = 0; kt2 < 4; ++kt2) {
            const int kt = kh * 4 + kt2;
            v4f acc = {0.0f, 0.0f, 0.0f, 0.0f};
#pragma unroll
            for (int ks = 0; ks < 4; ++ks) {
                v8s B = *(const v8s*)(WfC + (((size_t)kt * 4 + ks) * 64 + lane) * 8);
                acc = __builtin_amdgcn_mfma_f32_16x16x32_bf16(A[ks], B, acc, 0, 0, 0);
            }
#pragma unroll
            for (int r = 0; r < 4; ++r)
                zb[(wr * 16 + q * 4 + r) * 128 + kt * 16 + c] = f2bf(acc[r]);
        }
    }
}

// One block per (b, group of IB i's). Transposed MFMA formulation.
// T14 pipeline: dists(ii+1) global loads issue at head of GEMM1(ii) (regs),
// pack+LDS-write after sync2 (s_dists reads of ii all done), consumed next iter.
__global__ __launch_bounds__(256, 2) void k_cfconv_mfma(
    const float* __restrict__ dists,
    const float* __restrict__ kb1f, const float* __restrict__ kb2f,
    const unsigned short* __restrict__ zsbf,
    const unsigned short* __restrict__ kW1Tf,
    const unsigned short* __restrict__ kW2Tf,
    unsigned short* __restrict__ aggbf, int l) {
    __shared__ __align__(16) unsigned short s_dists[2560];   // [jt(5)][lane(64)][jj(8)]
    __shared__ __align__(16) unsigned short s_X1[10240];     // [jt(5)][ks(4)][lane(64)][jj(8)]

    const int blk = blockIdx.x;
    const int b = blk >> 3;          // 64/IB = 8 groups
    const int ig = blk & 7;
    const int t = threadIdx.x;
    const int lane = t & 63;
    const int w = t >> 6;
    const int q = lane >> 4;
    const int c = lane & 15;

    // --- per-block prelude: weights, biases, zs (amortized over IB i's) ---
    v8s a1[2], a2[2][4];
    {
        const uint4* w1p = (const uint4*)kW1Tf;
        const uint4* w2p = (const uint4*)kW2Tf;
#pragma unroll
        for (int t1 = 0; t1 < 2; ++t1) {
            uint4 u = w1p[(l * 8 + 2 * w + t1) * 64 + lane];
            a1[t1] = __builtin_bit_cast(v8s, u);
        }
#pragma unroll
        for (int mt = 0; mt < 2; ++mt)
#pragma unroll
            for (int ks = 0; ks < 4; ++ks) {
                uint4 u = w2p[((l * 8 + 2 * w + mt) * 4 + ks) * 64 + lane];
                a2[mt][ks] = __builtin_bit_cast(v8s, u);
            }
    }
    float4 kb1v[2], kb2v[2];
    {
        const float4* p1 = (const float4*)(kb1f + ((size_t)(l * 4 + w) * 64 + lane) * 8);
        kb1v[0] = p1[0];
        kb1v[1] = p1[1];
        const float4* p2 = (const float4*)(kb2f + ((size_t)(l * 4 + w) * 64 + lane) * 8);
        kb2v[0] = p2[0];
        kb2v[1] = p2[1];
    }
    // zs values exactly at this lane's reduce positions: row j=jt*16+c, col w*32+mt*16+q*4+r
    float zf[2][5][4];
    {
        const unsigned short* zb = zsbf + (size_t)b * (NPART * KD) + w * 32 + q * 4;
#pragma unroll
        for (int mt = 0; mt < 2; ++mt)
#pragma unroll
            for (int jt = 0; jt < 5; ++jt) {
                ushort4 zv = *(const ushort4*)(zb + (jt * 16 + c) * 128 + mt * 16);
                zf[mt][jt][0] = bf2f(zv.x);
                zf[mt][jt][1] = bf2f(zv.y);
                zf[mt][jt][2] = bf2f(zv.z);
                zf[mt][jt][3] = bf2f(zv.w);
            }
    }

    const float* dbase = dists + ((size_t)b * NELEC + ig * IB) * (NPART * NBASIS);

    // prologue: load + stage dists for ii=0
    float4 p0a, p0b, p1a, p1b;
    {
        const float* dj = dbase + (w * 16 + c) * 32 + q * 8;
        p0a = *(const float4*)dj;
        p0b = *(const float4*)(dj + 4);
        if (w == 0) {
            const float* dj4 = dbase + (64 + c) * 32 + q * 8;
            p1a = *(const float4*)dj4;
            p1b = *(const float4*)(dj4 + 4);
        }
    }
    {
        uint4 pk;
        pk.x = pk2(p0a.x, p0a.y); pk.y = pk2(p0a.z, p0a.w);
        pk.z = pk2(p0b.x, p0b.y); pk.w = pk2(p0b.z, p0b.w);
        *(uint4*)(s_dists + (w * 64 + lane) * 8) = pk;
        if (w == 0) {
            uint4 pk4;
            pk4.x = pk2(p1a.x, p1a.y); pk4.y = pk2(p1a.z, p1a.w);
            pk4.z = pk2(p1b.x, p1b.y); pk4.w = pk2(p1b.z, p1b.w);
            *(uint4*)(s_dists + (4 * 64 + lane) * 8) = pk4;
        }
    }

#pragma unroll 1
    for (int ii = 0; ii < IB; ++ii) {
        const int i = ig * IB + ii;
        __syncthreads();    // s_dists(ii) visible; s_X1 free for rewrite

        // issue next-i dists loads (fire-and-forget into regs; waited at packwrite)
        if (ii + 1 < IB) {
            const float* dg = dbase + (size_t)(ii + 1) * (NPART * NBASIS);
            const float* dj = dg + (w * 16 + c) * 32 + q * 8;
            p0a = *(const float4*)dj;
            p0b = *(const float4*)(dj + 4);
            if (w == 0) {
                const float* dj4 = dg + (64 + c) * 32 + q * 8;
                p1a = *(const float4*)dj4;
                p1b = *(const float4*)(dj4 + 4);
            }
        }

        // GEMM1-T: 10 MFMA, ssp, write X1 B-frags
#pragma unroll
        for (int jt = 0; jt < 5; ++jt) {
            v8s bd = *(const v8s*)(s_dists + (jt * 64 + lane) * 8);
#pragma unroll
            for (int t1 = 0; t1 < 2; ++t1) {
                v4f d = {kb1v[t1].x, kb1v[t1].y, kb1v[t1].z, kb1v[t1].w};
                d = __builtin_amdgcn_mfma_f32_16x16x32_bf16(a1[t1], bd, d, 0, 0, 0);
                uint2 o;
                o.x = pk2(sspf2(d[0]), sspf2(d[1]));
                o.y = pk2(sspf2(d[2]), sspf2(d[3]));
                int qB = 2 * t1 + (q >> 1);   // ks slice = w (wave owns kcols w*32..)
                *(uint2*)(s_X1 + ((jt * 4 + w) * 64 + qB * 16 + c) * 8 + (q & 1) * 4) = o;
            }
        }
        __syncthreads();    // X1 visible; s_dists(ii) reads all done

        // stage dists(ii+1) into s_dists (loads issued ~GEMM1 ago -> short wait)
        if (ii + 1 < IB) {
            uint4 pk;
            pk.x = pk2(p0a.x, p0a.y); pk.y = pk2(p0a.z, p0a.w);
            pk.z = pk2(p0b.x, p0b.y); pk.w = pk2(p0b.z, p0b.w);
            *(uint4*)(s_dists + (w * 64 + lane) * 8) = pk;
            if (w == 0) {
                uint4 pk4;
                pk4.x = pk2(p1a.x, p1a.y); pk4.y = pk2(p1a.z, p1a.w);
                pk4.z = pk2(p1b.x, p1b.y); pk4.w = pk2(p1b.z, p1b.w);
                *(uint4*)(s_dists + (4 * 64 + lane) * 8) = pk4;
            }
        }

        // GEMM2-T: 40 MFMA over (2 mt, 5 jt, 4 ks), full K sum per wave
        v4f acc[2][5];
#pragma unroll
        for (int mt = 0; mt < 2; ++mt)
#pragma unroll
            for (int jt = 0; jt < 5; ++jt)
                acc[mt][jt] = (v4f){(&kb2v[mt].x)[0], (&kb2v[mt].x)[1],
                                    (&kb2v[mt].x)[2], (&kb2v[mt].x)[3]};

#pragma unroll
        for (int jt = 0; jt < 5; ++jt) {
#pragma unroll
            for (int ks = 0; ks < 4; ++ks) {
                v8s bx = *(const v8s*)(s_X1 + ((jt * 4 + ks) * 64 + lane) * 8);
                acc[0][jt] = __builtin_amdgcn_mfma_f32_16x16x32_bf16(a2[0][ks], bx, acc[0][jt], 0, 0, 0);
                acc[1][jt] = __builtin_amdgcn_mfma_f32_16x16x32_bf16(a2[1][ks], bx, acc[1][jt], 0, 0, 0);
            }
        }

        // weighted reduce over j with the j==i diagonal masked (uniform-branched)
        float red[8];
#pragma unroll
        for (int v = 0; v < 8; ++v) red[v] = 0.0f;
        const int jt_i = i >> 4;
        const bool lanehit = (c == (i & 15));
#pragma unroll
        for (int jt = 0; jt < 5; ++jt) {
            if (jt == jt_i) {
#pragma unroll
                for (int mt = 0; mt < 2; ++mt)
#pragma unroll
                    for (int r = 0; r < 4; ++r) {
                        float a = lanehit ? 0.0f : acc[mt][jt][r];
                        red[mt * 4 + r] += a * zf[mt][jt][r];
                    }
            } else {
#pragma unroll
                for (int mt = 0; mt < 2; ++mt)
#pragma unroll
                    for (int r = 0; r < 4; ++r)
                        red[mt * 4 + r] += acc[mt][jt][r] * zf[mt][jt][r];
            }
        }

        // butterfly: 8 vals -> lane c holds value (c&7) summed over its 8-lane half,
        // then xor-8 add completes the 16-lane j sum.
        float vals[8];
#pragma unroll
        for (int v = 0; v < 8; ++v) vals[v] = red[v];
#pragma unroll
        for (int B = 0; B < 3; ++B) {
            const int off = 1 << B;
            const bool up = (c >> B) & 1;
#pragma unroll
            for (int k2 = 0; k2 < (4 >> B); ++k2) {
                float aa = vals[2 * k2], bb = vals[2 * k2 + 1];
                float mine = up ? bb : aa;
                float other = up ? aa : bb;
                vals[k2] = mine + __shfl_xor(other, off, 64);
            }
        }
        float x = vals[0] + __shfl_xor(vals[0], 8, 64);

        // lanes c<8 write this wave's 32 kcols: kcol = w*32 + ((c>>2)&1)*16 + q*4 + (c&3)
        if (c < 8) {
            int kcol = w * 32 + ((c >> 2) & 1) * 16 + q * 4 + (c & 3);
            aggbf[((size_t)b * NELEC + i) * 128 + kcol] = f2bf(x);
        }
    }
}

extern "C" void kernel_launch(void* const* d_in, const int* in_sizes, int n_in,
                              void* d_out, int out_size, void* d_ws, size_t ws_size,
                              hipStream_t stream) {
    const float* dists = (const float*)d_in[0];
    const float* emb_e = (const float*)d_in[1];
    const float* emb_n = (const float*)d_in[2];
    const float* kW1   = (const float*)d_in[3];
    const float* kb1   = (const float*)d_in[4];
    const float* kW2   = (const float*)d_in[5];
    const float* kb2   = (const float*)d_in[6];
    const float* eiW   = (const float*)d_in[7];
    const float* eoW1  = (const float*)d_in[8];
    const float* eob1  = (const float*)d_in[9];
    const float* eoW2  = (const float*)d_in[10];
    const float* eob2  = (const float*)d_in[11];

    float* xs = (float*)d_out;                                  // (256,64,128) f32
    unsigned short* zsbf  = (unsigned short*)d_ws;              // (256,80,128) bf16
    unsigned short* aggbf = zsbf + NBS * NPART * KD;            // (256,64,128) bf16
    unsigned short* hbf   = aggbf + NBS * NELEC * KD;           // (unused now)
    unsigned short* xs_bf = hbf + NBS * NELEC * KD;             // (256,64,128) bf16
    unsigned short* kW1Tf = xs_bf + NBS * NELEC * KD;           // 3*4096
    unsigned short* kW2Tf = kW1Tf + 3 * 4096;                   // 3*16384
    unsigned short* Wf    = kW2Tf + 3 * 16384;                  // 9*16384
    float* kb1f = (float*)(Wf + 9 * 16384);                     // 6144 f32
    float* kb2f = kb1f + 3 * 4 * 64 * 8;                        // 6144 f32

    k_init_xs<<<(NBS * NELEC * DD) / 256, 256, 0, stream>>>(emb_e, xs, xs_bf);
    k_prep<<<3, 256, 0, stream>>>(kW1, kW2, kW1Tf, kW2Tf);
    k_prep_w<<<9, 256, 0, stream>>>(eiW, eoW1, eoW2, Wf);
    k_prep_misc<<<1, 256, 0, stream>>>(kb1, kb2, kb1f, kb2f);
    k_nuc<<<(NBS * 16 * KD) / 256, 256, 0, stream>>>(emb_n, zsbf);

    // zs for layer 0
    k_gemm<0><<<NBS * 2, 256, 0, stream>>>(
        xs_bf, Wf + (size_t)(0 * 3 + 0) * 16384, nullptr, zsbf, nullptr, NPART * KD);

    for (int l = 0; l < 3; ++l) {
        k_cfconv_mfma<<<NBS * (NELEC / IB), 256, 0, stream>>>(
            dists, kb1f, kb2f, zsbf, kW1Tf, kW2Tf, aggbf, l);

        if (l < 2) {
            k_tail<0><<<NBS, 512, 0, stream>>>(
                aggbf,
                Wf + (size_t)(1 * 3 + l) * 16384, eob1 + l * DD,
                Wf + (size_t)(2 * 3 + l) * 16384, eob2 + l * DD,
                Wf + (size_t)(0 * 3 + (l + 1)) * 16384,
                xs, xs_bf, zsbf);
        } else {
            k_tail<1><<<NBS, 512, 0, stream>>>(
                aggbf,
                Wf + (size_t)(1 * 3 + l) * 16384, eob1 + l * DD,
                Wf + (size_t)(2 * 3 + l) * 16384, eob2 + l * DD,
                nullptr,
                xs, xs_bf, zsbf);
        }
    }
}